// Round 3
// baseline (505.246 us; speedup 1.0000x reference)
//
#include <hip/hip_runtime.h>
#include <math.h>

// Problem shape (fixed by reference setup_inputs):
//   images [32][256][64][64] fp32, words [32][32][768] fp32, mask [32][32] bool,
//   W [256][768] fp32, b [256] fp32
//   out0 weighted_words [32][256][64][64], out1 attn_out [32][32][64][64], fp32 concat.
#define B_   32
#define NC_  256
#define HW_  4096
#define MW_  32
#define E_   768
#define NEG_BIG -3.0e38f

// Workspace layout (float offsets). Total ~13.4 MB.
#define PART_OFF   0          // partial GEMM: 8 chunks * 32b * 32m * 256c = 2097152 floats
#define WP_OFF     2097152    // words_p [b][c][m]: 262144 floats
#define WT_OFF     2359296    // W transposed [e][c]: 196608 floats
#define WORDST_OFF 2555904    // words transposed [b][e][m]: 786432 floats
#define MASK_OFF   3342336    // normalized mask: 1024 ints

// ---------------------------------------------------------------------------
// Prep: tiled transposes (W 256x768 -> WT 768x256; words[b] 32x768 ->
// wordsT[b] 768x32) + mask normalization.
// ---------------------------------------------------------------------------
__global__ __launch_bounds__(256) void prep_kernel(
    const float* __restrict__ W, const float* __restrict__ words,
    const void* __restrict__ mask_raw,
    float* __restrict__ WT, float* __restrict__ wordsT,
    int* __restrict__ maskn) {
  const int tid = threadIdx.x;
  const int tx = tid & 31, ty = tid >> 5;
  if (blockIdx.x < 192) {
    __shared__ float t[32][33];
    const int tc = blockIdx.x / 24, te = blockIdx.x % 24;
    const int c0 = tc * 32, e0 = te * 32;
#pragma unroll
    for (int k = 0; k < 4; ++k) {
      const int r = ty + 8 * k;
      t[r][tx] = W[(c0 + r) * E_ + e0 + tx];
    }
    __syncthreads();
#pragma unroll
    for (int k = 0; k < 4; ++k) {
      const int r = ty + 8 * k;
      WT[(e0 + r) * NC_ + c0 + tx] = t[tx][r];
    }
  } else if (blockIdx.x < 960) {
    __shared__ float t[32][33];
    const int idx = blockIdx.x - 192;
    const int b = idx / 24, te = idx % 24;
    const int e0 = te * 32;
    const float* wsrc = words + (size_t)b * MW_ * E_;
    float* wdst = wordsT + (size_t)b * E_ * MW_;
#pragma unroll
    for (int k = 0; k < 4; ++k) {
      const int m = ty + 8 * k;
      t[m][tx] = wsrc[m * E_ + e0 + tx];
    }
    __syncthreads();
#pragma unroll
    for (int k = 0; k < 4; ++k) {
      const int e = ty + 8 * k;
      wdst[(e0 + e) * MW_ + tx] = t[tx][e];
    }
  } else {
    // Mask layout detection + normalize to int[1024].
    __shared__ int is_word;
    if (tid == 0) is_word = 1;
    __syncthreads();
    const int* mi = (const int*)mask_raw;
    const int v = mi[tid];
    if (v != 0 && v != 1 && v != 0x3F800000) is_word = 0;
    __syncthreads();
    if (is_word) {
#pragma unroll
      for (int j = 0; j < 4; ++j) { const int i = j * 256 + tid; maskn[i] = (mi[i] != 0); }
    } else {
      const unsigned char* mb = (const unsigned char*)mask_raw;
#pragma unroll
      for (int j = 0; j < 4; ++j) { const int i = j * 256 + tid; maskn[i] = (mb[i] != 0); }
    }
  }
}

// ---------------------------------------------------------------------------
// Stage 1a: words_p partials (unchanged from R2).
// ---------------------------------------------------------------------------
__global__ __launch_bounds__(256) void stage1_partial(
    const float* __restrict__ wordsT, const float* __restrict__ WT,
    float* __restrict__ part) {
  const int c = threadIdx.x;
  const int b = blockIdx.x >> 3;
  const int chunk = blockIdx.x & 7;
  const int e0 = chunk * 96;
  const float* wt = wordsT + (size_t)b * E_ * MW_;
  float acc[32];
#pragma unroll
  for (int m = 0; m < 32; ++m) acc[m] = 0.f;
#pragma unroll 2
  for (int e = e0; e < e0 + 96; ++e) {
    const float wv = WT[(size_t)e * NC_ + c];
    const float* wr = wt + e * MW_;
#pragma unroll
    for (int m = 0; m < 32; ++m) acc[m] = fmaf(wv, wr[m], acc[m]);
  }
  float* pp = part + ((size_t)chunk * 32 + b) * 32 * 256;
#pragma unroll
  for (int m = 0; m < 32; ++m) pp[m * 256 + c] = acc[m];
}

// ---------------------------------------------------------------------------
// Stage 1b: reduce 8 partials + bias -> wp[b][c][m] (unchanged from R2).
// ---------------------------------------------------------------------------
__global__ __launch_bounds__(256) void stage1_reduce(
    const float* __restrict__ part, const float* __restrict__ bias,
    float* __restrict__ wp) {
  const int idx = blockIdx.x * 256 + threadIdx.x;
  const int c = idx & 255;
  const int m = (idx >> 8) & 31;
  const int b = idx >> 13;
  float s = bias[c];
#pragma unroll
  for (int k = 0; k < 8; ++k)
    s += part[(((size_t)k * 32 + b) * 32 + m) * 256 + c];
  wp[((size_t)b * 256 + c) * 32 + m] = s;
}

// ---------------------------------------------------------------------------
// Fused attention. Block = 64 pixels x 4 waves; wave w owns c-chunk
// [64w, 64w+64) in BOTH the score pass and the output pass, so TLP (20
// waves/CU, LDS-capped) hides load latency instead of a register prefetch
// pipeline the compiler kept defeating (R2: VGPR=44, loads sunk to uses,
// 2.0 TB/s). Partial scores meet in a 32 KB LDS buffer; softmax is
// recomputed redundantly per wave (cheap: ~1k cyc) so no wave idles.
// All register arrays are constant-indexed (predicated stores for the
// wave-dependent attn planes) to avoid scratch spills.
// ---------------------------------------------------------------------------
__global__ __launch_bounds__(256) void attention_fused(
    const float* __restrict__ images, const float* __restrict__ wp,
    const int* __restrict__ maskn, float* __restrict__ out_w,
    float* __restrict__ out_a) {
  __shared__ float part[4][32][64];  // [wave][m][px]: lane-major -> conflict-free
  const int b = blockIdx.x >> 6;
  const int p0 = (blockIdx.x & 63) << 6;
  const int wv = threadIdx.x >> 6;
  const int ln = threadIdx.x & 63;
  const int p = p0 + ln;
  const float* img = images + ((size_t)(b * NC_ + (wv << 6))) * HW_ + p;
  const float* wpb = wp + (size_t)b * NC_ * MW_;

  // --- score partials over this wave's c-chunk ---
  float s[32];
#pragma unroll
  for (int m = 0; m < 32; ++m) s[m] = 0.f;
#pragma unroll 1
  for (int cc = 0; cc < 64; cc += 8) {
    float cur[8];
#pragma unroll
    for (int j = 0; j < 8; ++j)
      cur[j] = __builtin_nontemporal_load(img + (size_t)(cc + j) * HW_);
#pragma unroll
    for (int j = 0; j < 8; ++j) {
      const int c = (wv << 6) + cc + j;
#pragma unroll
      for (int m = 0; m < 32; ++m)
        s[m] = fmaf(cur[j], wpb[(c << 5) + m], s[m]);  // wpb -> s_load (SGPR)
    }
  }
#pragma unroll
  for (int m = 0; m < 32; ++m) part[wv][m][ln] = s[m];
  __syncthreads();

  // --- reduce partials (redundant in every wave) ---
#pragma unroll
  for (int m = 0; m < 32; ++m)
    s[m] = (part[0][m][ln] + part[1][m][ln]) + (part[2][m][ln] + part[3][m][ln]);

  // mask bits (wave-uniform)
  unsigned mbits = 0;
#pragma unroll
  for (int m = 0; m < 32; ++m)
    mbits |= (maskn[(b << 5) + m] != 0 ? 1u : 0u) << m;

  // softmax over m (scale 1/sqrt(256)); masked -> exactly 0
  float mx = NEG_BIG;
#pragma unroll
  for (int m = 0; m < 32; ++m) {
    s[m] *= 0.0625f;
    if (!((mbits >> m) & 1u)) mx = fmaxf(mx, s[m]);
  }
  float sum = 0.f;
#pragma unroll
  for (int m = 0; m < 32; ++m) {
    const float ev = ((mbits >> m) & 1u) ? 0.f : __expf(s[m] - mx);
    s[m] = ev;
    sum += ev;
  }
  const float inv = 1.f / sum;
#pragma unroll
  for (int m = 0; m < 32; ++m) {
    s[m] *= inv;
    if ((m >> 3) == wv)  // wave wv stores attn planes [8wv, 8wv+8)
      __builtin_nontemporal_store(s[m], out_a + ((size_t)(b * 32 + m) << 12) + p);
  }

  // --- weighted word sum over this wave's c-chunk ---
#pragma unroll 2
  for (int i = 0; i < 64; ++i) {
    const int c = (wv << 6) + i;
    float o = 0.f;
#pragma unroll
    for (int m = 0; m < 32; ++m)
      o = fmaf(wpb[(c << 5) + m], s[m], o);  // SGPR operand
    __builtin_nontemporal_store(o, out_w + ((size_t)(b * 256 + c) << 12) + p);
  }
}

// ---------------------------------------------------------------------------
extern "C" void kernel_launch(void* const* d_in, const int* in_sizes, int n_in,
                              void* d_out, int out_size, void* d_ws, size_t ws_size,
                              hipStream_t stream) {
  const float* images = (const float*)d_in[0];
  const float* words  = (const float*)d_in[1];
  const void*  mask   = d_in[2];
  const float* W      = (const float*)d_in[3];
  const float* bias   = (const float*)d_in[4];

  float* ws     = (float*)d_ws;
  float* part   = ws + PART_OFF;
  float* wp     = ws + WP_OFF;
  float* WT     = ws + WT_OFF;
  float* wordsT = ws + WORDST_OFF;
  int*   maskn  = (int*)(ws + MASK_OFF);

  float* out_w = (float*)d_out;
  float* out_a = out_w + (size_t)B_ * NC_ * HW_;

  prep_kernel<<<961, 256, 0, stream>>>(W, words, mask, WT, wordsT, maskn);
  stage1_partial<<<256, 256, 0, stream>>>(wordsT, WT, part);
  stage1_reduce<<<1024, 256, 0, stream>>>(part, bias, wp);
  attention_fused<<<2048, 256, 0, stream>>>(images, wp, maskn, out_w, out_a);
}